// Round 1
// baseline (650.794 us; speedup 1.0000x reference)
//
#include <hip/hip_runtime.h>

#define DIM 64

// ---------- pass 1: degree count (atomics into cnt) ----------
__global__ void degree_kernel(const int* __restrict__ row, int* __restrict__ cnt, int ne) {
    int i4 = (blockIdx.x * blockDim.x + threadIdx.x) * 4;
    if (i4 + 4 <= ne) {
        int4 r = *(const int4*)(row + i4);
        atomicAdd(&cnt[r.x], 1);
        atomicAdd(&cnt[r.y], 1);
        atomicAdd(&cnt[r.z], 1);
        atomicAdd(&cnt[r.w], 1);
    } else {
        for (int j = i4; j < ne; ++j) atomicAdd(&cnt[row[j]], 1);
    }
}

__global__ void dinv_kernel(const int* __restrict__ deg, float* __restrict__ dinv, int n) {
    int i = blockIdx.x * blockDim.x + threadIdx.x;
    if (i < n) {
        int d = deg[i];
        dinv[i] = d > 0 ? rsqrtf((float)d) : 0.0f;
    }
}

// ---------- exclusive scan of 16B-aligned row widths: off[r] = sum_{r'<r} align4(cnt[r']) ----------
__global__ void scan_blocks(const int* __restrict__ cnt, int* __restrict__ off,
                            int* __restrict__ bsum, int n) {
    __shared__ int s[256];
    int i = blockIdx.x * 256 + threadIdx.x;
    int w = 0;
    if (i < n) w = (cnt[i] + 3) & ~3;   // pad each row to multiple of 4 ints -> int4-aligned starts
    s[threadIdx.x] = w;
    __syncthreads();
    for (int d = 1; d < 256; d <<= 1) {
        int t = (threadIdx.x >= d) ? s[threadIdx.x - d] : 0;
        __syncthreads();
        s[threadIdx.x] += t;
        __syncthreads();
    }
    if (i < n) off[i] = s[threadIdx.x] - w;          // exclusive within block
    if (threadIdx.x == 255) bsum[blockIdx.x] = s[255];
}

__global__ void scan_tops(int* __restrict__ bsum, int nb_) {
    __shared__ int s[1024];
    int v = (threadIdx.x < nb_) ? bsum[threadIdx.x] : 0;
    s[threadIdx.x] = v;
    __syncthreads();
    for (int d = 1; d < 1024; d <<= 1) {
        int t = (threadIdx.x >= d) ? s[threadIdx.x - d] : 0;
        __syncthreads();
        s[threadIdx.x] += t;
        __syncthreads();
    }
    if (threadIdx.x < nb_) bsum[threadIdx.x] = s[threadIdx.x] - v;   // exclusive
}

__global__ void scan_add(int* __restrict__ off, const int* __restrict__ bsum, int n) {
    int i = blockIdx.x * blockDim.x + threadIdx.x;
    if (i < n) off[i] += bsum[blockIdx.x];
}

// ---------- pass 2: XCD-windowed CSR scatter ----------
// 8 consecutive blocks share one edge chunk; block b&7 only scatters rows in window b&7.
// CSR col array is compact (~15MB), so each XCD's write window (~1.8MB) is L2-resident
// -> kills the dirty-line write-back amplification the padded-ELL fill suffered (170MB -> ~18MB).
__global__ void csr_fill_xcd(const int* __restrict__ row, const int* __restrict__ col,
                             const int* __restrict__ off, int* __restrict__ cur,
                             int* __restrict__ csr, int ne, int chunk, int wsz) {
    int g = blockIdx.x >> 3;
    int w = blockIdx.x & 7;
    int lo = w * wsz;
    int hi = lo + wsz;
    int start = g * chunk;
    int end = min(ne, start + chunk);
    for (int i = start + threadIdx.x; i < end; i += blockDim.x) {
        int r = row[i];
        if (r >= lo && r < hi) {
            int c = col[i];
            int p = atomicAdd(&cur[r], 1);
            csr[off[r] + p] = c;
        }
    }
}

// concat user_emb and item_emb into x, float4-vectorized
__global__ void init_x_kernel(const float4* __restrict__ ue, const float4* __restrict__ ie,
                              float4* __restrict__ x, int nu4, int ntot4) {
    int i = blockIdx.x * blockDim.x + threadIdx.x;
    if (i < nu4) x[i] = ue[i];
    else if (i < ntot4) x[i] = ie[i - nu4];
}

// gather-SpMM over CSR: one wave per row, lane = feature, 8-deep gather pipeline.
// xn[r] = dinv[r] * sum_j dinv[c_j] * x[c_j]
__global__ void spmm_csr_kernel(const int* __restrict__ cnt, const int* __restrict__ off,
                                const int* __restrict__ csr, const float* __restrict__ dinv,
                                const float* __restrict__ x, float* __restrict__ xn, int nn) {
    int r = blockIdx.x * (blockDim.x >> 6) + (threadIdx.x >> 6);
    int lane = threadIdx.x & 63;
    if (r >= nn) return;
    int e = cnt[r];
    const int* erow = csr + off[r];          // off[r] is a multiple of 4 -> int4-aligned
    float a0 = 0.0f, a1 = 0.0f, a2 = 0.0f, a3 = 0.0f;
    int j = 0;
    for (; j + 8 <= e; j += 8) {
        int4 ca = *(const int4*)(erow + j);
        int4 cb = *(const int4*)(erow + j + 4);
        float v0 = dinv[ca.x], v1 = dinv[ca.y], v2 = dinv[ca.z], v3 = dinv[ca.w];
        float v4 = dinv[cb.x], v5 = dinv[cb.y], v6 = dinv[cb.z], v7 = dinv[cb.w];
        float x0 = x[(long)ca.x * DIM + lane];
        float x1 = x[(long)ca.y * DIM + lane];
        float x2 = x[(long)ca.z * DIM + lane];
        float x3 = x[(long)ca.w * DIM + lane];
        float x4 = x[(long)cb.x * DIM + lane];
        float x5 = x[(long)cb.y * DIM + lane];
        float x6 = x[(long)cb.z * DIM + lane];
        float x7 = x[(long)cb.w * DIM + lane];
        a0 += v0 * x0; a1 += v1 * x1; a2 += v2 * x2; a3 += v3 * x3;
        a0 += v4 * x4; a1 += v5 * x5; a2 += v6 * x6; a3 += v7 * x7;
    }
    for (; j + 4 <= e; j += 4) {
        int4 ca = *(const int4*)(erow + j);
        float v0 = dinv[ca.x], v1 = dinv[ca.y], v2 = dinv[ca.z], v3 = dinv[ca.w];
        a0 += v0 * x[(long)ca.x * DIM + lane];
        a1 += v1 * x[(long)ca.y * DIM + lane];
        a2 += v2 * x[(long)ca.z * DIM + lane];
        a3 += v3 * x[(long)ca.w * DIM + lane];
    }
    for (; j < e; ++j) {
        int c = erow[j];
        a0 += dinv[c] * x[(long)c * DIM + lane];
    }
    xn[(long)r * DIM + lane] = dinv[r] * ((a0 + a1) + (a2 + a3));
}

// layer-3 SpMM restricted to the 2*nb batch rows, accumulating straight into acc.
// x3 = A*x2 is only ever read at the gathered rows, so computing it for all 150K rows
// (a full ~145us SpMM) is wasted work -> do ~8192 rows (~8us) instead.
__global__ void spmm_rows_acc_kernel(const int* __restrict__ cnt, const int* __restrict__ off,
                                     const int* __restrict__ csr, const float* __restrict__ dinv,
                                     const float* __restrict__ x, const int* __restrict__ uidx,
                                     const int* __restrict__ iidx, float* __restrict__ acc,
                                     int nb, int nu) {
    int t = blockIdx.x * (blockDim.x >> 6) + (threadIdx.x >> 6);
    int lane = threadIdx.x & 63;
    if (t >= 2 * nb) return;
    int r = (t < nb) ? uidx[t] : nu + iidx[t - nb];
    int e = cnt[r];
    const int* erow = csr + off[r];
    float a0 = 0.0f, a1 = 0.0f, a2 = 0.0f, a3 = 0.0f;
    int j = 0;
    for (; j + 8 <= e; j += 8) {
        int4 ca = *(const int4*)(erow + j);
        int4 cb = *(const int4*)(erow + j + 4);
        float v0 = dinv[ca.x], v1 = dinv[ca.y], v2 = dinv[ca.z], v3 = dinv[ca.w];
        float v4 = dinv[cb.x], v5 = dinv[cb.y], v6 = dinv[cb.z], v7 = dinv[cb.w];
        a0 += v0 * x[(long)ca.x * DIM + lane];
        a1 += v1 * x[(long)ca.y * DIM + lane];
        a2 += v2 * x[(long)ca.z * DIM + lane];
        a3 += v3 * x[(long)ca.w * DIM + lane];
        a0 += v4 * x[(long)cb.x * DIM + lane];
        a1 += v5 * x[(long)cb.y * DIM + lane];
        a2 += v6 * x[(long)cb.z * DIM + lane];
        a3 += v7 * x[(long)cb.w * DIM + lane];
    }
    for (; j + 4 <= e; j += 4) {
        int4 ca = *(const int4*)(erow + j);
        a0 += dinv[ca.x] * x[(long)ca.x * DIM + lane];
        a1 += dinv[ca.y] * x[(long)ca.y * DIM + lane];
        a2 += dinv[ca.z] * x[(long)ca.z * DIM + lane];
        a3 += dinv[ca.w] * x[(long)ca.w * DIM + lane];
    }
    for (; j < e; ++j) {
        int c = erow[j];
        a0 += dinv[c] * x[(long)c * DIM + lane];
    }
    acc[(long)t * DIM + lane] += dinv[r] * ((a0 + a1) + (a2 + a3));
}

// accumulate x rows at the 2*nb gathered indices into acc (acc laid out [2*nb][DIM])
__global__ void gather_acc_kernel(const float* __restrict__ x, const int* __restrict__ uidx,
                                  const int* __restrict__ iidx, float* __restrict__ acc,
                                  int nb, int nu) {
    int t = blockIdx.x * blockDim.x + threadIdx.x;
    int b = t >> 6;
    int lane = t & 63;
    if (b < nb) {
        int r = uidx[b];
        acc[t] += x[(long)r * DIM + lane];
    } else if (b < 2 * nb) {
        int r = nu + iidx[b - nb];
        acc[t] += x[(long)r * DIM + lane];
    }
}

// scores[b] = dot(acc_u[b], acc_i[b]) / 16
__global__ void scores_kernel(const float* __restrict__ acc, float* __restrict__ out, int nb) {
    int b = blockIdx.x * (blockDim.x >> 6) + (threadIdx.x >> 6);
    int lane = threadIdx.x & 63;
    if (b >= nb) return;
    float p = acc[(long)b * DIM + lane] * acc[(long)(nb + b) * DIM + lane];
    #pragma unroll
    for (int off = 32; off; off >>= 1) p += __shfl_down(p, off);
    if (lane == 0) out[b] = p * 0.0625f;
}

extern "C" void kernel_launch(void* const* d_in, const int* in_sizes, int n_in,
                              void* d_out, int out_size, void* d_ws, size_t ws_size,
                              hipStream_t stream) {
    const float* user_emb = (const float*)d_in[0];
    const float* item_emb = (const float*)d_in[1];
    const int* edge_row = (const int*)d_in[2];
    const int* edge_col = (const int*)d_in[3];
    const int* user_idx = (const int*)d_in[4];
    const int* item_idx = (const int*)d_in[5];
    float* out = (float*)d_out;

    const int nu = in_sizes[0] / DIM;   // 100000
    const int ni = in_sizes[1] / DIM;   // 50000
    const int nn = nu + ni;             // 150000
    const int ne = in_sizes[2];         // 3200000
    const int nb = in_sizes[4];         // 4096

    char* ws = (char*)d_ws;
    size_t off_b = 0;
    auto alloc = [&](size_t bytes) -> void* {
        void* p = ws + off_b;
        off_b = (off_b + bytes + 255) & ~(size_t)255;
        return p;
    };
    int*   cnt  = (int*)  alloc((size_t)nn * 4);
    int*   cur  = (int*)  alloc((size_t)nn * 4);
    int*   roff = (int*)  alloc((size_t)nn * 4);
    float* dinv = (float*)alloc((size_t)nn * 4);
    int*   bsum = (int*)  alloc((size_t)1024 * 4);
    int*   csr  = (int*)  alloc(((size_t)ne + 4 * (size_t)nn) * 4);  // padded CSR cols ~15MB
    float* x0   = (float*)alloc((size_t)nn * DIM * 4);
    float* x1   = (float*)alloc((size_t)nn * DIM * 4);
    float* acc  = (float*)alloc((size_t)2 * nb * DIM * 4);

    hipMemsetAsync(cnt, 0, (size_t)nn * 4, stream);
    hipMemsetAsync(cur, 0, (size_t)nn * 4, stream);
    hipMemsetAsync(acc, 0, (size_t)2 * nb * DIM * 4, stream);

    // --- degrees + dinv ---
    degree_kernel<<<(ne / 4 + 255) / 256, 256, 0, stream>>>(edge_row, cnt, ne);
    dinv_kernel<<<(nn + 255) / 256, 256, 0, stream>>>(cnt, dinv, nn);

    // --- exclusive scan of aligned widths -> row offsets ---
    const int nblk = (nn + 255) / 256;      // 586 <= 1024
    scan_blocks<<<nblk, 256, 0, stream>>>(cnt, roff, bsum, nn);
    scan_tops<<<1, 1024, 0, stream>>>(bsum, nblk);
    scan_add<<<nblk, 256, 0, stream>>>(roff, bsum, nn);

    // --- build CSR adjacency, XCD-window partitioned ---
    const int ngroups = 256;
    const int chunk = (ne + ngroups - 1) / ngroups;   // 12500
    const int wsz = (nn + 7) / 8;                     // 18750 rows per XCD window (~1.8MB CSR span)
    csr_fill_xcd<<<ngroups * 8, 256, 0, stream>>>(edge_row, edge_col, roff, cur, csr, ne, chunk, wsz);

    // --- init x ---
    const int ntot4 = nn * DIM / 4;
    const int nu4 = nu * DIM / 4;
    init_x_kernel<<<(ntot4 + 255) / 256, 256, 0, stream>>>(
        (const float4*)user_emb, (const float4*)item_emb, (float4*)x0, nu4, ntot4);

    gather_acc_kernel<<<(2 * nb * DIM + 255) / 256, 256, 0, stream>>>(
        x0, user_idx, item_idx, acc, nb, nu);

    // --- 2 full propagation layers ---
    float* xa = x0;
    float* xb = x1;
    for (int l = 0; l < 2; ++l) {
        spmm_csr_kernel<<<(nn + 3) / 4, 256, 0, stream>>>(cnt, roff, csr, dinv, xa, xb, nn);
        gather_acc_kernel<<<(2 * nb * DIM + 255) / 256, 256, 0, stream>>>(
            xb, user_idx, item_idx, acc, nb, nu);
        float* t = xa; xa = xb; xb = t;
    }

    // --- layer 3: only the 8192 batch rows are ever read -> mini-SpMM straight into acc ---
    spmm_rows_acc_kernel<<<(2 * nb + 3) / 4, 256, 0, stream>>>(
        cnt, roff, csr, dinv, xa, user_idx, item_idx, acc, nb, nu);

    scores_kernel<<<(nb + 3) / 4, 256, 0, stream>>>(acc, out, nb);
}

// Round 2
// 452.429 us; speedup vs baseline: 1.4384x; 1.4384x over previous
//
#include <hip/hip_runtime.h>

#define DIM 64
#define BSH 8            // bucket = row >> 8  (256 rows per bucket)
#define MAXNB 1024       // bucket-count cap (nn <= 256K)
#define NBLKA 256        // blocks in binning passes A1/A2
#define BKT_SLACK 768    // per-bucket alignment slack: 256 rows * 3 pad max
#define MAXT 11264       // max padded slots per bucket (44KB LDS); mean item bucket = 8192

// ---------- A1: per-block bucket histogram (LDS atomics only) ----------
__global__ void binA1(const int* __restrict__ row, int* __restrict__ blkhist,
                      int ne, int chunk, int nbk) {
    __shared__ int h[MAXNB];
    for (int k = threadIdx.x; k < nbk; k += blockDim.x) h[k] = 0;
    __syncthreads();
    int start = blockIdx.x * chunk, end = min(ne, start + chunk);
    for (int i = start + threadIdx.x; i < end; i += blockDim.x)
        atomicAdd(&h[row[i] >> BSH], 1);
    __syncthreads();
    for (int k = threadIdx.x; k < nbk; k += blockDim.x)
        blkhist[blockIdx.x * nbk + k] = h[k];
}

// ---------- R: per-bucket exclusive scan across the 256 blocks ----------
__global__ void binR(int* __restrict__ blkhist, int* __restrict__ bktraw, int nbk) {
    __shared__ int s[NBLKA];
    int k = blockIdx.x;
    int v = blkhist[threadIdx.x * nbk + k];
    s[threadIdx.x] = v;
    __syncthreads();
    for (int d = 1; d < NBLKA; d <<= 1) {
        int t = (threadIdx.x >= d) ? s[threadIdx.x - d] : 0;
        __syncthreads();
        s[threadIdx.x] += t;
        __syncthreads();
    }
    blkhist[threadIdx.x * nbk + k] = s[threadIdx.x] - v;   // exclusive rel start
    if (threadIdx.x == NBLKA - 1) bktraw[k] = s[NBLKA - 1];
}

// ---------- S: exclusive scan of slacked bucket sizes -> bucket bases ----------
__global__ void binS(const int* __restrict__ bktraw, int* __restrict__ bktbase, int nbk) {
    __shared__ int s[MAXNB];
    int v = 0;
    if ((int)threadIdx.x < nbk) v = (bktraw[threadIdx.x] + BKT_SLACK + 3) & ~3;
    s[threadIdx.x] = v;
    __syncthreads();
    for (int d = 1; d < MAXNB; d <<= 1) {
        int t = (threadIdx.x >= d) ? s[threadIdx.x - d] : 0;
        __syncthreads();
        s[threadIdx.x] += t;
        __syncthreads();
    }
    if ((int)threadIdx.x < nbk) bktbase[threadIdx.x] = s[threadIdx.x] - v;
}

// ---------- A2: scatter edges into bucket regions (LDS cursors, no device atomics) ----------
// bin entry: (local_row << 24) | col   (col < 150000 < 2^24)
__global__ void binA2(const int* __restrict__ row, const int* __restrict__ col,
                      const int* __restrict__ blkhist, const int* __restrict__ bktbase,
                      unsigned int* __restrict__ bin, int ne, int chunk, int nbk) {
    __shared__ int cur[MAXNB];
    for (int k = threadIdx.x; k < nbk; k += blockDim.x)
        cur[k] = bktbase[k] + blkhist[blockIdx.x * nbk + k];
    __syncthreads();
    int start = blockIdx.x * chunk, end = min(ne, start + chunk);
    for (int i = start + threadIdx.x; i < end; i += blockDim.x) {
        int r = row[i];
        int k = r >> BSH;
        int p = atomicAdd(&cur[k], 1);
        bin[p] = ((unsigned)(r & 255) << 24) | (unsigned)col[i];
    }
}

// ---------- B: per-bucket CSR build fully in LDS; also emits cnt/roff/dinv ----------
__global__ void csr_build(const unsigned int* __restrict__ bin, const int* __restrict__ bktraw,
                          const int* __restrict__ bktbase, int* __restrict__ csr,
                          int* __restrict__ cnt, int* __restrict__ roff,
                          float* __restrict__ dinv, int nn) {
    __shared__ int rc[256];
    __shared__ int sc[256];
    __shared__ int rcur[256];
    __shared__ int Tt;
    __shared__ alignas(16) int scsr[MAXT];
    int k = blockIdx.x;
    int base = bktbase[k];
    int nraw = bktraw[k];
    rc[threadIdx.x] = 0;
    __syncthreads();
    // count phase
    for (int i = threadIdx.x; i < nraw; i += 256)
        atomicAdd(&rc[bin[base + i] >> 24], 1);
    __syncthreads();
    // scan of int4-padded row widths
    int w = (rc[threadIdx.x] + 3) & ~3;
    sc[threadIdx.x] = w;
    __syncthreads();
    for (int d = 1; d < 256; d <<= 1) {
        int t = (threadIdx.x >= d) ? sc[threadIdx.x - d] : 0;
        __syncthreads();
        sc[threadIdx.x] += t;
        __syncthreads();
    }
    int myoff = sc[threadIdx.x] - w;
    if (threadIdx.x == 255) Tt = sc[255];
    rcur[threadIdx.x] = myoff;
    int r = (k << BSH) + threadIdx.x;
    if (r < nn) {
        int d = rc[threadIdx.x];
        cnt[r] = d;
        roff[r] = base + myoff;
        dinv[r] = d > 0 ? rsqrtf((float)d) : 0.0f;
    }
    __syncthreads();
    // scatter phase into LDS CSR
    for (int i = threadIdx.x; i < nraw; i += 256) {
        unsigned u = bin[base + i];
        int rl = u >> 24;
        int p = atomicAdd(&rcur[rl], 1);
        scsr[p] = (int)(u & 0xFFFFFFu);
    }
    __syncthreads();
    // coalesced int4 copy to global
    int T = Tt;
    for (int i = threadIdx.x; i * 4 < T; i += 256)
        ((int4*)(csr + base))[i] = ((const int4*)scsr)[i];
}

// concat user_emb and item_emb into x, float4-vectorized
__global__ void init_x_kernel(const float4* __restrict__ ue, const float4* __restrict__ ie,
                              float4* __restrict__ x, int nu4, int ntot4) {
    int i = blockIdx.x * blockDim.x + threadIdx.x;
    if (i < nu4) x[i] = ue[i];
    else if (i < ntot4) x[i] = ie[i - nu4];
}

// gather-SpMM over CSR: one wave per row, lane = feature, 8-deep gather pipeline.
__global__ void spmm_csr_kernel(const int* __restrict__ cnt, const int* __restrict__ off,
                                const int* __restrict__ csr, const float* __restrict__ dinv,
                                const float* __restrict__ x, float* __restrict__ xn, int nn) {
    int r = blockIdx.x * (blockDim.x >> 6) + (threadIdx.x >> 6);
    int lane = threadIdx.x & 63;
    if (r >= nn) return;
    int e = cnt[r];
    const int* erow = csr + off[r];
    float a0 = 0.0f, a1 = 0.0f, a2 = 0.0f, a3 = 0.0f;
    int j = 0;
    for (; j + 8 <= e; j += 8) {
        int4 ca = *(const int4*)(erow + j);
        int4 cb = *(const int4*)(erow + j + 4);
        float v0 = dinv[ca.x], v1 = dinv[ca.y], v2 = dinv[ca.z], v3 = dinv[ca.w];
        float v4 = dinv[cb.x], v5 = dinv[cb.y], v6 = dinv[cb.z], v7 = dinv[cb.w];
        float x0 = x[(long)ca.x * DIM + lane];
        float x1 = x[(long)ca.y * DIM + lane];
        float x2 = x[(long)ca.z * DIM + lane];
        float x3 = x[(long)ca.w * DIM + lane];
        float x4 = x[(long)cb.x * DIM + lane];
        float x5 = x[(long)cb.y * DIM + lane];
        float x6 = x[(long)cb.z * DIM + lane];
        float x7 = x[(long)cb.w * DIM + lane];
        a0 += v0 * x0; a1 += v1 * x1; a2 += v2 * x2; a3 += v3 * x3;
        a0 += v4 * x4; a1 += v5 * x5; a2 += v6 * x6; a3 += v7 * x7;
    }
    for (; j + 4 <= e; j += 4) {
        int4 ca = *(const int4*)(erow + j);
        float v0 = dinv[ca.x], v1 = dinv[ca.y], v2 = dinv[ca.z], v3 = dinv[ca.w];
        a0 += v0 * x[(long)ca.x * DIM + lane];
        a1 += v1 * x[(long)ca.y * DIM + lane];
        a2 += v2 * x[(long)ca.z * DIM + lane];
        a3 += v3 * x[(long)ca.w * DIM + lane];
    }
    for (; j < e; ++j) {
        int c = erow[j];
        a0 += dinv[c] * x[(long)c * DIM + lane];
    }
    xn[(long)r * DIM + lane] = dinv[r] * ((a0 + a1) + (a2 + a3));
}

// layer-3 SpMM restricted to the 2*nb batch rows, accumulating straight into acc.
__global__ void spmm_rows_acc_kernel(const int* __restrict__ cnt, const int* __restrict__ off,
                                     const int* __restrict__ csr, const float* __restrict__ dinv,
                                     const float* __restrict__ x, const int* __restrict__ uidx,
                                     const int* __restrict__ iidx, float* __restrict__ acc,
                                     int nb, int nu) {
    int t = blockIdx.x * (blockDim.x >> 6) + (threadIdx.x >> 6);
    int lane = threadIdx.x & 63;
    if (t >= 2 * nb) return;
    int r = (t < nb) ? uidx[t] : nu + iidx[t - nb];
    int e = cnt[r];
    const int* erow = csr + off[r];
    float a0 = 0.0f, a1 = 0.0f, a2 = 0.0f, a3 = 0.0f;
    int j = 0;
    for (; j + 8 <= e; j += 8) {
        int4 ca = *(const int4*)(erow + j);
        int4 cb = *(const int4*)(erow + j + 4);
        a0 += dinv[ca.x] * x[(long)ca.x * DIM + lane];
        a1 += dinv[ca.y] * x[(long)ca.y * DIM + lane];
        a2 += dinv[ca.z] * x[(long)ca.z * DIM + lane];
        a3 += dinv[ca.w] * x[(long)ca.w * DIM + lane];
        a0 += dinv[cb.x] * x[(long)cb.x * DIM + lane];
        a1 += dinv[cb.y] * x[(long)cb.y * DIM + lane];
        a2 += dinv[cb.z] * x[(long)cb.z * DIM + lane];
        a3 += dinv[cb.w] * x[(long)cb.w * DIM + lane];
    }
    for (; j + 4 <= e; j += 4) {
        int4 ca = *(const int4*)(erow + j);
        a0 += dinv[ca.x] * x[(long)ca.x * DIM + lane];
        a1 += dinv[ca.y] * x[(long)ca.y * DIM + lane];
        a2 += dinv[ca.z] * x[(long)ca.z * DIM + lane];
        a3 += dinv[ca.w] * x[(long)ca.w * DIM + lane];
    }
    for (; j < e; ++j) {
        int c = erow[j];
        a0 += dinv[c] * x[(long)c * DIM + lane];
    }
    acc[(long)t * DIM + lane] += dinv[r] * ((a0 + a1) + (a2 + a3));
}

// accumulate x rows at the 2*nb gathered indices into acc
__global__ void gather_acc_kernel(const float* __restrict__ x, const int* __restrict__ uidx,
                                  const int* __restrict__ iidx, float* __restrict__ acc,
                                  int nb, int nu) {
    int t = blockIdx.x * blockDim.x + threadIdx.x;
    int b = t >> 6;
    int lane = t & 63;
    if (b < nb) {
        int r = uidx[b];
        acc[t] += x[(long)r * DIM + lane];
    } else if (b < 2 * nb) {
        int r = nu + iidx[b - nb];
        acc[t] += x[(long)r * DIM + lane];
    }
}

// scores[b] = dot(acc_u[b], acc_i[b]) / 16
__global__ void scores_kernel(const float* __restrict__ acc, float* __restrict__ out, int nb) {
    int b = blockIdx.x * (blockDim.x >> 6) + (threadIdx.x >> 6);
    int lane = threadIdx.x & 63;
    if (b >= nb) return;
    float p = acc[(long)b * DIM + lane] * acc[(long)(nb + b) * DIM + lane];
    #pragma unroll
    for (int off = 32; off; off >>= 1) p += __shfl_down(p, off);
    if (lane == 0) out[b] = p * 0.0625f;
}

extern "C" void kernel_launch(void* const* d_in, const int* in_sizes, int n_in,
                              void* d_out, int out_size, void* d_ws, size_t ws_size,
                              hipStream_t stream) {
    const float* user_emb = (const float*)d_in[0];
    const float* item_emb = (const float*)d_in[1];
    const int* edge_row = (const int*)d_in[2];
    const int* edge_col = (const int*)d_in[3];
    const int* user_idx = (const int*)d_in[4];
    const int* item_idx = (const int*)d_in[5];
    float* out = (float*)d_out;

    const int nu = in_sizes[0] / DIM;   // 100000
    const int ni = in_sizes[1] / DIM;   // 50000
    const int nn = nu + ni;             // 150000
    const int ne = in_sizes[2];         // 3200000
    const int nb = in_sizes[4];         // 4096

    const int nbk = (nn + 255) >> BSH;              // 586 buckets
    const int chunkA = (ne + NBLKA - 1) / NBLKA;    // 12500

    char* ws = (char*)d_ws;
    size_t off_b = 0;
    auto alloc = [&](size_t bytes) -> void* {
        void* p = ws + off_b;
        off_b = (off_b + bytes + 255) & ~(size_t)255;
        return p;
    };
    size_t csr_entries = (size_t)ne + (size_t)nbk * (BKT_SLACK + 4);

    int*   cnt     = (int*)  alloc((size_t)nn * 4);
    int*   roff    = (int*)  alloc((size_t)nn * 4);
    float* dinv    = (float*)alloc((size_t)nn * 4);
    int*   bktraw  = (int*)  alloc((size_t)MAXNB * 4);
    int*   bktbase = (int*)  alloc((size_t)MAXNB * 4);
    int*   blkhist = (int*)  alloc((size_t)NBLKA * nbk * 4);
    int*   csr     = (int*)  alloc(csr_entries * 4);
    float* x0      = (float*)alloc((size_t)nn * DIM * 4);
    // bin (consumed by csr_build) unioned with x1 (first written by SpMM layer 1)
    size_t bin_bytes = csr_entries * 4;
    size_t x1_bytes  = (size_t)nn * DIM * 4;
    char*  uni     = (char*) alloc(bin_bytes > x1_bytes ? bin_bytes : x1_bytes);
    unsigned int* bin = (unsigned int*)uni;
    float* x1      = (float*)uni;
    float* acc     = (float*)alloc((size_t)2 * nb * DIM * 4);

    hipMemsetAsync(acc, 0, (size_t)2 * nb * DIM * 4, stream);

    // --- binned CSR build: no device atomics, L2-friendly burst writes ---
    binA1<<<NBLKA, 256, 0, stream>>>(edge_row, blkhist, ne, chunkA, nbk);
    binR <<<nbk, NBLKA, 0, stream>>>(blkhist, bktraw, nbk);
    binS <<<1, MAXNB, 0, stream>>>(bktraw, bktbase, nbk);
    binA2<<<NBLKA, 256, 0, stream>>>(edge_row, edge_col, blkhist, bktbase, bin, ne, chunkA, nbk);
    csr_build<<<nbk, 256, 0, stream>>>(bin, bktraw, bktbase, csr, cnt, roff, dinv, nn);

    // --- init x ---
    const int ntot4 = nn * DIM / 4;
    const int nu4 = nu * DIM / 4;
    init_x_kernel<<<(ntot4 + 255) / 256, 256, 0, stream>>>(
        (const float4*)user_emb, (const float4*)item_emb, (float4*)x0, nu4, ntot4);

    gather_acc_kernel<<<(2 * nb * DIM + 255) / 256, 256, 0, stream>>>(
        x0, user_idx, item_idx, acc, nb, nu);

    // --- 2 full propagation layers ---
    float* xa = x0;
    float* xb = x1;
    for (int l = 0; l < 2; ++l) {
        spmm_csr_kernel<<<(nn + 3) / 4, 256, 0, stream>>>(cnt, roff, csr, dinv, xa, xb, nn);
        gather_acc_kernel<<<(2 * nb * DIM + 255) / 256, 256, 0, stream>>>(
            xb, user_idx, item_idx, acc, nb, nu);
        float* t = xa; xa = xb; xb = t;
    }

    // --- layer 3: only the 8192 batch rows are ever read -> mini-SpMM into acc ---
    spmm_rows_acc_kernel<<<(2 * nb + 3) / 4, 256, 0, stream>>>(
        cnt, roff, csr, dinv, xa, user_idx, item_idx, acc, nb, nu);

    scores_kernel<<<(nb + 3) / 4, 256, 0, stream>>>(acc, out, nb);
}

// Round 3
// 368.331 us; speedup vs baseline: 1.7669x; 1.2283x over previous
//
#include <hip/hip_runtime.h>
#include <hip/hip_fp16.h>

#define DIM 64
#define BSH 8            // bucket = row >> 8  (256 rows per bucket)
#define MAXNB 1024       // bucket-count cap (nn <= 256K)
#define NBLKA 256        // blocks in binning passes A1/A2
#define BKT_SLACK 768    // per-bucket alignment slack: 256 rows * 3 pad max
#define MAXT 11264       // max padded slots per bucket (44KB LDS)

// ---------- A1: per-block bucket histogram (LDS atomics only) ----------
__global__ void binA1(const int* __restrict__ row, int* __restrict__ blkhist,
                      int ne, int chunk, int nbk) {
    __shared__ int h[MAXNB];
    for (int k = threadIdx.x; k < nbk; k += blockDim.x) h[k] = 0;
    __syncthreads();
    int start = blockIdx.x * chunk, end = min(ne, start + chunk);
    for (int i = start + threadIdx.x; i < end; i += blockDim.x)
        atomicAdd(&h[row[i] >> BSH], 1);
    __syncthreads();
    for (int k = threadIdx.x; k < nbk; k += blockDim.x)
        blkhist[blockIdx.x * nbk + k] = h[k];
}

// ---------- R: per-bucket exclusive scan across the 256 blocks ----------
__global__ void binR(int* __restrict__ blkhist, int* __restrict__ bktraw, int nbk) {
    __shared__ int s[NBLKA];
    int k = blockIdx.x;
    int v = blkhist[threadIdx.x * nbk + k];
    s[threadIdx.x] = v;
    __syncthreads();
    for (int d = 1; d < NBLKA; d <<= 1) {
        int t = (threadIdx.x >= d) ? s[threadIdx.x - d] : 0;
        __syncthreads();
        s[threadIdx.x] += t;
        __syncthreads();
    }
    blkhist[threadIdx.x * nbk + k] = s[threadIdx.x] - v;   // exclusive rel start
    if (threadIdx.x == NBLKA - 1) bktraw[k] = s[NBLKA - 1];
}

// ---------- S: exclusive scan of slacked bucket sizes -> bucket bases ----------
__global__ void binS(const int* __restrict__ bktraw, int* __restrict__ bktbase, int nbk) {
    __shared__ int s[MAXNB];
    int v = 0;
    if ((int)threadIdx.x < nbk) v = (bktraw[threadIdx.x] + BKT_SLACK + 3) & ~3;
    s[threadIdx.x] = v;
    __syncthreads();
    for (int d = 1; d < MAXNB; d <<= 1) {
        int t = (threadIdx.x >= d) ? s[threadIdx.x - d] : 0;
        __syncthreads();
        s[threadIdx.x] += t;
        __syncthreads();
    }
    if ((int)threadIdx.x < nbk) bktbase[threadIdx.x] = s[threadIdx.x] - v;
}

// ---------- A2: scatter edges into bucket regions (LDS cursors, no device atomics) ----------
// bin entry: (local_row << 24) | col   (col < 150000 < 2^24)
__global__ void binA2(const int* __restrict__ row, const int* __restrict__ col,
                      const int* __restrict__ blkhist, const int* __restrict__ bktbase,
                      unsigned int* __restrict__ bin, int ne, int chunk, int nbk) {
    __shared__ int cur[MAXNB];
    for (int k = threadIdx.x; k < nbk; k += blockDim.x)
        cur[k] = bktbase[k] + blkhist[blockIdx.x * nbk + k];
    __syncthreads();
    int start = blockIdx.x * chunk, end = min(ne, start + chunk);
    for (int i = start + threadIdx.x; i < end; i += blockDim.x) {
        int r = row[i];
        int k = r >> BSH;
        int p = atomicAdd(&cur[k], 1);
        bin[p] = ((unsigned)(r & 255) << 24) | (unsigned)col[i];
    }
}

// ---------- B: per-bucket CSR build fully in LDS; also emits cnt/roff/dinv/sqd ----------
__global__ void csr_build(const unsigned int* __restrict__ bin, const int* __restrict__ bktraw,
                          const int* __restrict__ bktbase, int* __restrict__ csr,
                          int* __restrict__ cnt, int* __restrict__ roff,
                          float* __restrict__ dinv, float* __restrict__ sqd, int nn) {
    __shared__ int rc[256];
    __shared__ int sc[256];
    __shared__ int rcur[256];
    __shared__ int Tt;
    __shared__ alignas(16) int scsr[MAXT];
    int k = blockIdx.x;
    int base = bktbase[k];
    int nraw = bktraw[k];
    rc[threadIdx.x] = 0;
    __syncthreads();
    for (int i = threadIdx.x; i < nraw; i += 256)
        atomicAdd(&rc[bin[base + i] >> 24], 1);
    __syncthreads();
    int w = (rc[threadIdx.x] + 3) & ~3;
    sc[threadIdx.x] = w;
    __syncthreads();
    for (int d = 1; d < 256; d <<= 1) {
        int t = (threadIdx.x >= d) ? sc[threadIdx.x - d] : 0;
        __syncthreads();
        sc[threadIdx.x] += t;
        __syncthreads();
    }
    int myoff = sc[threadIdx.x] - w;
    if (threadIdx.x == 255) Tt = sc[255];
    rcur[threadIdx.x] = myoff;
    int r = (k << BSH) + threadIdx.x;
    if (r < nn) {
        int d = rc[threadIdx.x];
        cnt[r] = d;
        roff[r] = base + myoff;
        dinv[r] = d > 0 ? rsqrtf((float)d) : 0.0f;
        sqd[r]  = d > 0 ? sqrtf((float)d)  : 0.0f;
    }
    __syncthreads();
    for (int i = threadIdx.x; i < nraw; i += 256) {
        unsigned u = bin[base + i];
        int rl = u >> 24;
        int p = atomicAdd(&rcur[rl], 1);
        scsr[p] = (int)(u & 0xFFFFFFu);
    }
    __syncthreads();
    int T = Tt;
    for (int i = threadIdx.x; i * 4 < T; i += 256)
        ((int4*)(csr + base))[i] = ((const int4*)scsr)[i];
}

// ---------- mark rows whose y2 is consumed: batch rows + their neighbors ----------
__global__ void mark_kernel(const int* __restrict__ cnt, const int* __restrict__ off,
                            const int* __restrict__ csr, const int* __restrict__ uidx,
                            const int* __restrict__ iidx, unsigned char* __restrict__ flag,
                            int nb, int nu) {
    int t = blockIdx.x * (blockDim.x >> 6) + (threadIdx.x >> 6);
    int lane = threadIdx.x & 63;
    if (t >= 2 * nb) return;
    int r = (t < nb) ? uidx[t] : nu + iidx[t - nb];
    if (lane == 0) flag[r] = 1;
    int e = cnt[r];
    const int* erow = csr + off[r];
    for (int j = lane; j < e; j += 64) flag[erow[j]] = 1;
}

// ---------- init: y0[r] = half(dinv[r] * emb[r]), fused concat + prescale ----------
__global__ void init_y_kernel(const float2* __restrict__ ue2, const float2* __restrict__ ie2,
                              const float* __restrict__ dinv, __half2* __restrict__ y,
                              int nu, int nn) {
    int t = blockIdx.x * blockDim.x + threadIdx.x;    // nn * 32 threads, float2 each
    if (t >= nn * 32) return;
    int r = t >> 5;
    float2 v = (r < nu) ? ue2[t] : ie2[t - nu * 32];
    float d = dinv[r];
    y[t] = __floats2half2_rn(d * v.x, d * v.y);
}

// gather-SpMM over CSR, fp16 prescaled source: y_out[r] = half(dinv[r]^2 * sum_j y[c_j])
// flag != nullptr -> compute only flagged rows (layer-2 sparsification)
__global__ void spmm_half_kernel(const int* __restrict__ cnt, const int* __restrict__ off,
                                 const int* __restrict__ csr, const float* __restrict__ dinv,
                                 const __half* __restrict__ y, __half* __restrict__ yn,
                                 const unsigned char* __restrict__ flag, int nn) {
    int r = blockIdx.x * (blockDim.x >> 6) + (threadIdx.x >> 6);
    int lane = threadIdx.x & 63;
    if (r >= nn) return;
    if (flag && !flag[r]) return;
    int e = cnt[r];
    const int* erow = csr + off[r];
    float a0 = 0.0f, a1 = 0.0f, a2 = 0.0f, a3 = 0.0f;
    int j = 0;
    for (; j + 8 <= e; j += 8) {
        int4 ca = *(const int4*)(erow + j);
        int4 cb = *(const int4*)(erow + j + 4);
        float x0 = __half2float(y[(long)ca.x * DIM + lane]);
        float x1 = __half2float(y[(long)ca.y * DIM + lane]);
        float x2 = __half2float(y[(long)ca.z * DIM + lane]);
        float x3 = __half2float(y[(long)ca.w * DIM + lane]);
        float x4 = __half2float(y[(long)cb.x * DIM + lane]);
        float x5 = __half2float(y[(long)cb.y * DIM + lane]);
        float x6 = __half2float(y[(long)cb.z * DIM + lane]);
        float x7 = __half2float(y[(long)cb.w * DIM + lane]);
        a0 += x0; a1 += x1; a2 += x2; a3 += x3;
        a0 += x4; a1 += x5; a2 += x6; a3 += x7;
    }
    for (; j + 4 <= e; j += 4) {
        int4 ca = *(const int4*)(erow + j);
        a0 += __half2float(y[(long)ca.x * DIM + lane]);
        a1 += __half2float(y[(long)ca.y * DIM + lane]);
        a2 += __half2float(y[(long)ca.z * DIM + lane]);
        a3 += __half2float(y[(long)ca.w * DIM + lane]);
    }
    for (; j < e; ++j) {
        a0 += __half2float(y[(long)erow[j] * DIM + lane]);
    }
    float d = dinv[r];
    yn[(long)r * DIM + lane] = __float2half(d * d * ((a0 + a1) + (a2 + a3)));
}

// layer-3 restricted to the 2*nb batch rows: acc += dinv[r] * sum_j y2[c_j]
__global__ void spmm_rows_acc_kernel(const int* __restrict__ cnt, const int* __restrict__ off,
                                     const int* __restrict__ csr, const float* __restrict__ dinv,
                                     const __half* __restrict__ y, const int* __restrict__ uidx,
                                     const int* __restrict__ iidx, float* __restrict__ acc,
                                     int nb, int nu) {
    int t = blockIdx.x * (blockDim.x >> 6) + (threadIdx.x >> 6);
    int lane = threadIdx.x & 63;
    if (t >= 2 * nb) return;
    int r = (t < nb) ? uidx[t] : nu + iidx[t - nb];
    int e = cnt[r];
    const int* erow = csr + off[r];
    float a0 = 0.0f, a1 = 0.0f, a2 = 0.0f, a3 = 0.0f;
    int j = 0;
    for (; j + 8 <= e; j += 8) {
        int4 ca = *(const int4*)(erow + j);
        int4 cb = *(const int4*)(erow + j + 4);
        a0 += __half2float(y[(long)ca.x * DIM + lane]);
        a1 += __half2float(y[(long)ca.y * DIM + lane]);
        a2 += __half2float(y[(long)ca.z * DIM + lane]);
        a3 += __half2float(y[(long)ca.w * DIM + lane]);
        a0 += __half2float(y[(long)cb.x * DIM + lane]);
        a1 += __half2float(y[(long)cb.y * DIM + lane]);
        a2 += __half2float(y[(long)cb.z * DIM + lane]);
        a3 += __half2float(y[(long)cb.w * DIM + lane]);
    }
    for (; j + 4 <= e; j += 4) {
        int4 ca = *(const int4*)(erow + j);
        a0 += __half2float(y[(long)ca.x * DIM + lane]);
        a1 += __half2float(y[(long)ca.y * DIM + lane]);
        a2 += __half2float(y[(long)ca.z * DIM + lane]);
        a3 += __half2float(y[(long)ca.w * DIM + lane]);
    }
    for (; j < e; ++j) {
        a0 += __half2float(y[(long)erow[j] * DIM + lane]);
    }
    acc[(long)t * DIM + lane] += dinv[r] * ((a0 + a1) + (a2 + a3));
}

// ---------- layer-0 acc: read embeddings directly (fp32 exact), first write ----------
__global__ void gather_acc0(const float* __restrict__ ue, const float* __restrict__ ie,
                            const int* __restrict__ uidx, const int* __restrict__ iidx,
                            float* __restrict__ acc, int nb, int nu) {
    int t = blockIdx.x * blockDim.x + threadIdx.x;
    int b = t >> 6;
    int lane = t & 63;
    if (b < nb) acc[t] = ue[(long)uidx[b] * DIM + lane];
    else if (b < 2 * nb) acc[t] = ie[(long)iidx[b - nb] * DIM + lane];
}

// ---------- layers 1,2 acc: x_l[r] = y_l[r] * sqrt(deg_r) ----------
__global__ void gather_acc_y(const __half* __restrict__ y, const float* __restrict__ sqd,
                             const int* __restrict__ uidx, const int* __restrict__ iidx,
                             float* __restrict__ acc, int nb, int nu) {
    int t = blockIdx.x * blockDim.x + threadIdx.x;
    int b = t >> 6;
    int lane = t & 63;
    if (b >= 2 * nb) return;
    int r = (b < nb) ? uidx[b] : nu + iidx[b - nb];
    acc[t] += __half2float(y[(long)r * DIM + lane]) * sqd[r];
}

// scores[b] = dot(acc_u[b], acc_i[b]) / 16
__global__ void scores_kernel(const float* __restrict__ acc, float* __restrict__ out, int nb) {
    int b = blockIdx.x * (blockDim.x >> 6) + (threadIdx.x >> 6);
    int lane = threadIdx.x & 63;
    if (b >= nb) return;
    float p = acc[(long)b * DIM + lane] * acc[(long)(nb + b) * DIM + lane];
    #pragma unroll
    for (int off = 32; off; off >>= 1) p += __shfl_down(p, off);
    if (lane == 0) out[b] = p * 0.0625f;
}

extern "C" void kernel_launch(void* const* d_in, const int* in_sizes, int n_in,
                              void* d_out, int out_size, void* d_ws, size_t ws_size,
                              hipStream_t stream) {
    const float* user_emb = (const float*)d_in[0];
    const float* item_emb = (const float*)d_in[1];
    const int* edge_row = (const int*)d_in[2];
    const int* edge_col = (const int*)d_in[3];
    const int* user_idx = (const int*)d_in[4];
    const int* item_idx = (const int*)d_in[5];
    float* out = (float*)d_out;

    const int nu = in_sizes[0] / DIM;   // 100000
    const int ni = in_sizes[1] / DIM;   // 50000
    const int nn = nu + ni;             // 150000
    const int ne = in_sizes[2];         // 3200000
    const int nb = in_sizes[4];         // 4096

    const int nbk = (nn + 255) >> BSH;              // 586 buckets
    const int chunkA = (ne + NBLKA - 1) / NBLKA;    // 12500

    char* ws = (char*)d_ws;
    size_t off_b = 0;
    auto alloc = [&](size_t bytes) -> void* {
        void* p = ws + off_b;
        off_b = (off_b + bytes + 255) & ~(size_t)255;
        return p;
    };
    size_t csr_entries = (size_t)ne + (size_t)nbk * (BKT_SLACK + 4);

    int*   cnt     = (int*)  alloc((size_t)nn * 4);
    int*   roff    = (int*)  alloc((size_t)nn * 4);
    float* dinv    = (float*)alloc((size_t)nn * 4);
    float* sqd     = (float*)alloc((size_t)nn * 4);
    unsigned char* flag = (unsigned char*)alloc((size_t)nn);
    int*   bktraw  = (int*)  alloc((size_t)MAXNB * 4);
    int*   bktbase = (int*)  alloc((size_t)MAXNB * 4);
    int*   blkhist = (int*)  alloc((size_t)NBLKA * nbk * 4);
    int*   csr     = (int*)  alloc(csr_entries * 4);
    // bin (consumed by csr_build) unioned with ya (first written by init_y, after csr_build)
    size_t bin_bytes = csr_entries * 4;
    size_t y_bytes  = (size_t)nn * DIM * 2;
    char*  uni     = (char*) alloc(bin_bytes > y_bytes ? bin_bytes : y_bytes);
    unsigned int* bin = (unsigned int*)uni;
    __half* ya     = (__half*)uni;
    __half* yb     = (__half*)alloc(y_bytes);
    float* acc     = (float*)alloc((size_t)2 * nb * DIM * 4);

    hipMemsetAsync(flag, 0, (size_t)nn, stream);

    // --- binned CSR build: no device atomics, L2-friendly burst writes ---
    binA1<<<NBLKA, 256, 0, stream>>>(edge_row, blkhist, ne, chunkA, nbk);
    binR <<<nbk, NBLKA, 0, stream>>>(blkhist, bktraw, nbk);
    binS <<<1, MAXNB, 0, stream>>>(bktraw, bktbase, nbk);
    binA2<<<NBLKA, 256, 0, stream>>>(edge_row, edge_col, blkhist, bktbase, bin, ne, chunkA, nbk);
    csr_build<<<nbk, 256, 0, stream>>>(bin, bktraw, bktbase, csr, cnt, roff, dinv, sqd, nn);

    // --- mark rows whose y2 is consumed (batch + neighbors) ---
    mark_kernel<<<(2 * nb + 3) / 4, 256, 0, stream>>>(cnt, roff, csr, user_idx, item_idx,
                                                      flag, nb, nu);

    // --- init y0 = half(dinv * emb) (overwrites bin region; csr_build already consumed it) ---
    init_y_kernel<<<(nn * 32 + 255) / 256, 256, 0, stream>>>(
        (const float2*)user_emb, (const float2*)item_emb, dinv, (__half2*)ya, nu, nn);

    // --- layer 0 acc: exact fp32 embeddings ---
    gather_acc0<<<(2 * nb * DIM + 255) / 256, 256, 0, stream>>>(
        user_emb, item_emb, user_idx, item_idx, acc, nb, nu);

    // --- layer 1 (full) ---
    spmm_half_kernel<<<(nn + 3) / 4, 256, 0, stream>>>(cnt, roff, csr, dinv, ya, yb,
                                                       (const unsigned char*)nullptr, nn);
    gather_acc_y<<<(2 * nb * DIM + 255) / 256, 256, 0, stream>>>(
        yb, sqd, user_idx, item_idx, acc, nb, nu);

    // --- layer 2 (restricted to flagged ~69% of rows) ---
    spmm_half_kernel<<<(nn + 3) / 4, 256, 0, stream>>>(cnt, roff, csr, dinv, yb, ya, flag, nn);
    gather_acc_y<<<(2 * nb * DIM + 255) / 256, 256, 0, stream>>>(
        ya, sqd, user_idx, item_idx, acc, nb, nu);

    // --- layer 3: only the 8192 batch rows are ever read -> mini-SpMM into acc ---
    spmm_rows_acc_kernel<<<(2 * nb + 3) / 4, 256, 0, stream>>>(
        cnt, roff, csr, dinv, ya, user_idx, item_idx, acc, nb, nu);

    scores_kernel<<<(nb + 3) / 4, 256, 0, stream>>>(acc, out, nb);
}